// Round 6
// baseline (725.650 us; speedup 1.0000x reference)
//
#include <hip/hip_runtime.h>

// Problem constants (from reference)
#define BATCH 2048
#define T 512
#define NF 10
#define HID 30
#define S3T 1536          // 3*T sequence length after reshape/transpose
#define FEAT_PER_B 15360  // 10*1536 features per batch element
// Workspace: BATCH * FEAT_PER_B * 2 = 62,914,560 bytes (f16 xpair)
// Layout: xpair[b][p][s][e] (p<5, s<1536, e<2) = f16 x[b][s][2p+e].
// One uint4 (16B) at stream p, chunk c = d-pair (2p,2p+1) for steps 4c..4c+3.

typedef _Float16 v2h __attribute__((ext_vector_type(2)));

#define LOG2E 1.44269504088896f

__device__ __forceinline__ float fexp(float x) {
    return __builtin_amdgcn_exp2f(x * LOG2E);   // v_exp_f32
}
__device__ __forceinline__ float frcp(float x) {
    return __builtin_amdgcn_rcpf(x);            // v_rcp_f32
}
__device__ __forceinline__ float fd(v2h a, v2h b, float c) {
    return __builtin_amdgcn_fdot2(a, b, c, false);
}

// Session ledger (R18-R23):
//  - real VALU busy = VALUBusy/2 (gfx94x SIMD-16 formula on SIMD-32 HW).
//  - R18 lockstep 2-batch/wave: wall 597-608 cyc/step, busy ~190-221.
//  - split-K (R19/R22) and DPP reg-gather (R20/R22): issue-bloat, lose.
//  - R23 dot-chain tree: NEUTRAL -> spine is NOT the fdot2 dep chain; it is
//    the LDS h-broadcast round trip + the h-dependent issue block + trans
//    chain, none of which overlaps anything in a single in-order chain.
// R24: TWO independent chains per wave (4 batches), interleaved at source.
// A's LDS-read latency overlaps B's; B's compute fills A's stalls. Weights
// shared (same unit mapping) -> only x-streams/h/hbuf duplicate.

// Kernel 1: transpose-through-LDS [R15: 89 -> ~19us], f16 out [R16].
__global__ void __launch_bounds__(512)
feat_kernel(const int* __restrict__ atom_i,
            const int* __restrict__ atom_j,
            const float* __restrict__ dist,
            const float* __restrict__ emb,
            uint4* __restrict__ xpair8) {
    __shared__ float lf[512 * 31 + 30];   // slot(t,c) = t*31 + c
    const int b = blockIdx.x;
    const int t = threadIdx.x;

    {
        const int bt = b * T + t;
        const int ai = atom_i[bt];
        const int aj = atom_j[bt];
        const float dd = dist[bt];
        const float mi = (ai != 0) ? 1.0f : 0.0f;
        const float mj = (aj != 0) ? 1.0f : 0.0f;
        const float* ei = &emb[ai * NF];
        const float* ej = &emb[aj * NF];
        float* row = &lf[t * 31];
#pragma unroll
        for (int c = 0; c < NF; ++c) row[c] = mi * ei[c];
#pragma unroll
        for (int c = 0; c < NF; ++c) row[10 + c] = mj * ej[c];
#pragma unroll
        for (int c = 0; c < NF; ++c) {
            float ctr = (float)(c + 1) * 0.7f;
            float df = ctr - dd;
            row[20 + c] = mi * fexp(-df * df);
        }
    }
    __syncthreads();

    uint4* ob = xpair8 + (long)b * 1920;
    for (int o = t; o < 1920; o += 512) {
        unsigned p  = (unsigned)o / 384u;
        unsigned c4 = (unsigned)o - p * 384u;
        union { _Float16 h[8]; uint4 u; } pk;
#pragma unroll
        for (int kx = 0; kx < 8; ++kx) {
            unsigned s = 4u * c4 + (unsigned)(kx >> 1);
            unsigned e = (unsigned)(kx & 1);
            unsigned f = (2u * p + e) * 1536u + s;
            unsigned tt = f / 30u;            // compiler -> magic mul
            unsigned cc = f - tt * 30u;
            pk.h[kx] = (_Float16)lf[tt * 31u + cc];
        }
        ob[o] = pk.u;
    }
}

// One fused superstep: one GRU step for BOTH chains, interleaved so each
// chain's stalls are filled by the other chain's independent issue.
// Program order: both ds_read_b128 pairs first (latencies overlap), both
// x-unpacks + ih dots (no h dependency -> fill the read window), hh dots A
// then hh dots B (B's issue covers A's tree latency), gates A then gates B
// (B's trans ops fill A's exp2/rcp chain stalls), writes, one fence.
// R23's 4-way tree accumulation kept (free variance reduction).
#define STEP2(PAR, XQA, XQB, IDX)                                            \
    {                                                                        \
        const uint4* hvA = (const uint4*)&hbufA[PAR][half * 32];             \
        uint4 ta0 = hvA[0], ta1 = hvA[1], ta2 = hvA[2], ta3 = hvA[3];        \
        const uint4* hvB = (const uint4*)&hbufB[PAR][half * 32];             \
        uint4 tb0 = hvB[0], tb1 = hvB[1], tb2 = hvB[2], tb3 = hvB[3];        \
        v2h xcA[5], xcB[5];                                                  \
        _Pragma("unroll")                                                    \
        for (int pp = 0; pp < 5; ++pp) {                                     \
            unsigned wa = ((const unsigned*)&XQA[pp])[IDX];                  \
            __builtin_memcpy(&xcA[pp], &wa, 4);                              \
            unsigned wb = ((const unsigned*)&XQB[pp])[IDX];                  \
            __builtin_memcpy(&xcB[pp], &wb, 4);                              \
        }                                                                    \
        float arA0 = brf, azA0 = bzf, aiA = bif, ahA0 = bhf;                 \
        float arB0 = brf, azB0 = bzf, aiB = bif, ahB0 = bhf;                 \
        _Pragma("unroll")                                                    \
        for (int d = 0; d < 5; ++d) {                                        \
            arA0 = fd(wir[d], xcA[d], arA0);                                 \
            azA0 = fd(wiz[d], xcA[d], azA0);                                 \
            aiA  = fd(win[d], xcA[d], aiA);                                  \
            arB0 = fd(wir[d], xcB[d], arB0);                                 \
            azB0 = fd(wiz[d], xcB[d], azB0);                                 \
            aiB  = fd(win[d], xcB[d], aiB);                                  \
        }                                                                    \
        v2h hjA[16];                                                         \
        __builtin_memcpy(&hjA[0], &ta0, 16);                                 \
        __builtin_memcpy(&hjA[4], &ta1, 16);                                 \
        __builtin_memcpy(&hjA[8], &ta2, 16);                                 \
        __builtin_memcpy(&hjA[12], &ta3, 16);                                \
        float arA1 = 0.0f, arA2 = 0.0f, arA3 = 0.0f;                         \
        float azA1 = 0.0f, azA2 = 0.0f, azA3 = 0.0f;                         \
        float ahA1 = 0.0f, ahA2 = 0.0f;                                      \
        _Pragma("unroll")                                                    \
        for (int j = 0; j < 5; ++j) {                                        \
            arA1 = fd(whr[j], hjA[j], arA1);                                 \
            azA1 = fd(whz[j], hjA[j], azA1);                                 \
            ahA0 = fd(whn[j], hjA[j], ahA0);                                 \
        }                                                                    \
        _Pragma("unroll")                                                    \
        for (int j = 5; j < 10; ++j) {                                       \
            arA2 = fd(whr[j], hjA[j], arA2);                                 \
            azA2 = fd(whz[j], hjA[j], azA2);                                 \
            ahA1 = fd(whn[j], hjA[j], ahA1);                                 \
        }                                                                    \
        _Pragma("unroll")                                                    \
        for (int j = 10; j < 15; ++j) {                                      \
            arA3 = fd(whr[j], hjA[j], arA3);                                 \
            azA3 = fd(whz[j], hjA[j], azA3);                                 \
            ahA2 = fd(whn[j], hjA[j], ahA2);                                 \
        }                                                                    \
        v2h hjB[16];                                                         \
        __builtin_memcpy(&hjB[0], &tb0, 16);                                 \
        __builtin_memcpy(&hjB[4], &tb1, 16);                                 \
        __builtin_memcpy(&hjB[8], &tb2, 16);                                 \
        __builtin_memcpy(&hjB[12], &tb3, 16);                                \
        float arB1 = 0.0f, arB2 = 0.0f, arB3 = 0.0f;                         \
        float azB1 = 0.0f, azB2 = 0.0f, azB3 = 0.0f;                         \
        float ahB1 = 0.0f, ahB2 = 0.0f;                                      \
        _Pragma("unroll")                                                    \
        for (int j = 0; j < 5; ++j) {                                        \
            arB1 = fd(whr[j], hjB[j], arB1);                                 \
            azB1 = fd(whz[j], hjB[j], azB1);                                 \
            ahB0 = fd(whn[j], hjB[j], ahB0);                                 \
        }                                                                    \
        _Pragma("unroll")                                                    \
        for (int j = 5; j < 10; ++j) {                                       \
            arB2 = fd(whr[j], hjB[j], arB2);                                 \
            azB2 = fd(whz[j], hjB[j], azB2);                                 \
            ahB1 = fd(whn[j], hjB[j], ahB1);                                 \
        }                                                                    \
        _Pragma("unroll")                                                    \
        for (int j = 10; j < 15; ++j) {                                      \
            arB3 = fd(whr[j], hjB[j], arB3);                                 \
            azB3 = fd(whz[j], hjB[j], azB3);                                 \
            ahB2 = fd(whn[j], hjB[j], ahB2);                                 \
        }                                                                    \
        float arA = (arA0 + arA1) + (arA2 + arA3);                           \
        float azA = (azA0 + azA1) + (azA2 + azA3);                           \
        float ahA = (ahA0 + ahA1) + ahA2;                                    \
        float erA = __builtin_amdgcn_exp2f(arA);                             \
        float ezA = __builtin_amdgcn_exp2f(azA);                             \
        float arB = (arB0 + arB1) + (arB2 + arB3);                           \
        float azB = (azB0 + azB1) + (azB2 + azB3);                           \
        float ahB = (ahB0 + ahB1) + ahB2;                                    \
        float erB = __builtin_amdgcn_exp2f(arB);                             \
        float ezB = __builtin_amdgcn_exp2f(azB);                             \
        float rgA = frcp(1.0f + erA);                                        \
        float zgA = frcp(1.0f + ezA);                                        \
        float rgB = frcp(1.0f + erB);                                        \
        float zgB = frcp(1.0f + ezB);                                        \
        float ngA = 2.0f * frcp(1.0f +                                       \
                    __builtin_amdgcn_exp2f(aiA + rgA * ahA)) - 1.0f;         \
        float ngB = 2.0f * frcp(1.0f +                                       \
                    __builtin_amdgcn_exp2f(aiB + rgB * ahB)) - 1.0f;         \
        hA = ngA + zgA * (hA - ngA);                                         \
        hB = ngB + zgB * (hB - ngB);                                         \
        hbufA[(PAR) ^ 1][half * 32 + k] = (_Float16)hA;                      \
        hbufB[(PAR) ^ 1][half * 32 + k] = (_Float16)hB;                      \
        __builtin_amdgcn_fence(__ATOMIC_ACQ_REL, "wavefront");               \
    }

// Kernel 2: GRU recurrence — R24: 4 batches per wave as TWO independent
// interleaved chains (each chain = R18's lockstep 2-batch full-dot mapping:
// lane k of each half computes all gates for unit k of its half's batch).
// 512 single-wave blocks. Weights/biases are chain-invariant (same kk) so
// register cost of the 2nd chain is only its x ping-pong (+40 VGPR), h, and
// a 256B hbuf. Time = 1536 supersteps x wall; wave count (512 of 1024
// SIMDs) is immaterial. waves_per_eu(1,1): full VGPR budget for one wave.
__attribute__((amdgpu_waves_per_eu(1, 1)))
__global__ void __launch_bounds__(64)
gru_kernel(const _Float16* __restrict__ xpair,
           const float* __restrict__ W_ih,   // [90,10]
           const float* __restrict__ W_hh,   // [90,30]
           const float* __restrict__ b_ih,   // [90]
           const float* __restrict__ b_hh,   // [90]
           const float* __restrict__ W_out,  // [1,30]
           const float* __restrict__ b_out,  // [1]
           float* __restrict__ out) {
    __shared__ __align__(16) _Float16 hbufA[2][64];
    __shared__ __align__(16) _Float16 hbufB[2][64];
    const int lane = threadIdx.x;
    const int half = lane >> 5;
    const int k    = lane & 31;
    const bool active = (k < HID);
    const int kk = active ? k : (HID - 1);
    const int bA = blockIdx.x * 4 + half;      // chain A batches: 4B, 4B+1
    const int bB = bA + 2;                     // chain B batches: 4B+2, 4B+3

    const float SRZ = -LOG2E;          // sigmoid(x) = rcp(1+exp2(-L x))
    const float SN  = -2.0f * LOG2E;   // tanh(u) = 2 rcp(1+exp2(-2L u)) - 1

    // hh weights: 15 v2h (j-pairs) per gate, prescaled in f32 then RNE->f16.
    v2h whr[15], whz[15], whn[15];
    {
        const float2* Rr = (const float2*)&W_hh[(0 * HID + kk) * HID];
        const float2* Rz = (const float2*)&W_hh[(1 * HID + kk) * HID];
        const float2* Rn = (const float2*)&W_hh[(2 * HID + kk) * HID];
#pragma unroll
        for (int j = 0; j < 15; ++j) {
            float2 tr = Rr[j], tz = Rz[j], tn = Rn[j];
            whr[j] = (v2h){(_Float16)(tr.x * SRZ), (_Float16)(tr.y * SRZ)};
            whz[j] = (v2h){(_Float16)(tz.x * SRZ), (_Float16)(tz.y * SRZ)};
            whn[j] = (v2h){(_Float16)(tn.x * SN),  (_Float16)(tn.y * SN)};
        }
    }
    // ih weights: 5 v2h per gate (d-pairs match xpair layout).
    v2h wir[5], wiz[5], win[5];
    {
        const float2* Rr = (const float2*)&W_ih[(0 * HID + kk) * NF];
        const float2* Rz = (const float2*)&W_ih[(1 * HID + kk) * NF];
        const float2* Rn = (const float2*)&W_ih[(2 * HID + kk) * NF];
#pragma unroll
        for (int d = 0; d < 5; ++d) {
            float2 tr = Rr[d], tz = Rz[d], tn = Rn[d];
            wir[d] = (v2h){(_Float16)(tr.x * SRZ), (_Float16)(tr.y * SRZ)};
            wiz[d] = (v2h){(_Float16)(tz.x * SRZ), (_Float16)(tz.y * SRZ)};
            win[d] = (v2h){(_Float16)(tn.x * SN),  (_Float16)(tn.y * SN)};
        }
    }
    // Biases (prescaled, f32 — fdot2's accumulator seed). Chain-invariant.
    const float brf = SRZ * (b_ih[0 * HID + kk] + b_hh[0 * HID + kk]);
    const float bzf = SRZ * (b_ih[1 * HID + kk] + b_hh[1 * HID + kk]);
    const float bif = SN * b_ih[2 * HID + kk];  // n biases stay split:
    const float bhf = SN * b_hh[2 * HID + kk];  // n uses ai + rg*ah

    // Per-chain chunk streams: x[p][c] = uint4 = d-pair (2p,2p+1), steps
    // 4c..4c+3.
    const _Float16* xbA = xpair + (long)bA * FEAT_PER_B;
    const _Float16* xbB = xpair + (long)bB * FEAT_PER_B;
    const uint4* xaA[5];
    const uint4* xaB[5];
#pragma unroll
    for (int p = 0; p < 5; ++p) {
        xaA[p] = (const uint4*)(xbA + p * 3072);
        xaB[p] = (const uint4*)(xbB + p * 3072);
    }

    hbufA[0][lane] = (_Float16)0.0f;
    hbufA[1][lane] = (_Float16)0.0f;
    hbufB[0][lane] = (_Float16)0.0f;
    hbufB[1][lane] = (_Float16)0.0f;
    __builtin_amdgcn_fence(__ATOMIC_ACQ_REL, "wavefront");

    float hA = 0.0f, hB = 0.0f;
    uint4 xqA0[5], xqA1[5], xqB0[5], xqB1[5];
#pragma unroll
    for (int p = 0; p < 5; ++p) {
        xqA0[p] = xaA[p][0];
        xqB0[p] = xaB[p][0];
    }

    // 384 chunks of 4 supersteps, ping-pong pairs (xq*0/xq*1 alternate
    // roles — no register rotation [R18]). 384 is even; prefetch c2+1 is
    // always in range, tail prefetch c2+2 clamps to 383.
    for (int c2 = 0; c2 < 384; c2 += 2) {
#pragma unroll
        for (int p = 0; p < 5; ++p) {
            xqA1[p] = xaA[p][c2 + 1];
            xqB1[p] = xaB[p][c2 + 1];
        }
        STEP2(0, xqA0, xqB0, 0);
        STEP2(1, xqA0, xqB0, 1);
        STEP2(0, xqA0, xqB0, 2);
        STEP2(1, xqA0, xqB0, 3);
        const int cn = (c2 + 2 < 384) ? (c2 + 2) : 383;
#pragma unroll
        for (int p = 0; p < 5; ++p) {
            xqA0[p] = xaA[p][cn];
            xqB0[p] = xaB[p][cn];
        }
        STEP2(0, xqA1, xqB1, 0);
        STEP2(1, xqA1, xqB1, 1);
        STEP2(0, xqA1, xqB1, 2);
        STEP2(1, xqA1, xqB1, 3);
    }

    // out[b] = relu(h . W_out + b_out), reduced within each 32-lane half,
    // once per chain.
    {
        float v = active ? hA * W_out[kk] : 0.0f;
#pragma unroll
        for (int off = 16; off; off >>= 1) v += __shfl_xor(v, off, 32);
        if (k == 0) {
            float o = v + b_out[0];
            out[bA] = o > 0.0f ? o : 0.0f;
        }
    }
    {
        float v = active ? hB * W_out[kk] : 0.0f;
#pragma unroll
        for (int off = 16; off; off >>= 1) v += __shfl_xor(v, off, 32);
        if (k == 0) {
            float o = v + b_out[0];
            out[bB] = o > 0.0f ? o : 0.0f;
        }
    }
}

extern "C" void kernel_launch(void* const* d_in, const int* in_sizes, int n_in,
                              void* d_out, int out_size, void* d_ws, size_t ws_size,
                              hipStream_t stream) {
    const int* atom_i   = (const int*)d_in[0];
    const int* atom_j   = (const int*)d_in[1];
    const float* dist   = (const float*)d_in[2];
    const float* emb    = (const float*)d_in[3];
    const float* W_ih   = (const float*)d_in[4];
    const float* W_hh   = (const float*)d_in[5];
    const float* b_ih   = (const float*)d_in[6];
    const float* b_hh   = (const float*)d_in[7];
    const float* W_out  = (const float*)d_in[8];
    const float* b_out  = (const float*)d_in[9];
    float* out = (float*)d_out;
    _Float16* xpair = (_Float16*)d_ws;   // 62,914,560 B

    feat_kernel<<<BATCH, 512, 0, stream>>>(atom_i, atom_j, dist, emb,
                                           (uint4*)xpair);
    gru_kernel<<<BATCH / 4, 64, 0, stream>>>(xpair, W_ih, W_hh, b_ih, b_hh,
                                             W_out, b_out, out);
}

// Round 8
// 707.549 us; speedup vs baseline: 1.0256x; 1.0256x over previous
//
#include <hip/hip_runtime.h>

// Problem constants (from reference)
#define BATCH 2048
#define T 512
#define NF 10
#define HID 30
#define S3T 1536          // 3*T sequence length after reshape/transpose
#define FEAT_PER_B 15360  // 10*1536 features per batch element
// Workspace: BATCH * FEAT_PER_B * 2 = 62,914,560 bytes (f16 xpair)
// Layout: xpair[b][p][s][e] (p<5, s<1536, e<2) = f16 x[b][s][2p+e].
// One uint4 (16B) at stream p, chunk c = d-pair (2p,2p+1) for steps 4c..4c+3.

typedef _Float16 v2h __attribute__((ext_vector_type(2)));

#define LOG2E 1.44269504088896f

__device__ __forceinline__ float fexp(float x) {
    return __builtin_amdgcn_exp2f(x * LOG2E);   // v_exp_f32
}
__device__ __forceinline__ float frcp(float x) {
    return __builtin_amdgcn_rcpf(x);            // v_rcp_f32
}
__device__ __forceinline__ float fd(v2h a, v2h b, float c) {
    return __builtin_amdgcn_fdot2(a, b, c, false);
}

// Session ledger (R18-R25):
//  - real VALU busy = VALUBusy/2 (gfx94x SIMD-16 formula on SIMD-32 HW).
//  - R18 lockstep 2-batch/wave: wall 597-608 cyc/step, busy ~190-221 -> the
//    ~380-cyc stall is the LDS h round trip + trans/gate chain.
//  - split-K (R19/R22), DPP reg-gather (R20/R22): issue-bloat, lose.
//  - R23 tree: NEUTRAL -> the fdot2 dep chain is NOT the spine.
//  - R24 dual-chain: VGPR stayed 132 -> compiler SANK the prefetch loads to
//    their uses (demand latency, chains serialized). Never executed as
//    designed.
//  - R25: "+v" tie on uint4 is unsupported (tied indirect reg inputs).
// R26 = R25 with the rule-18 wait idiom: volatile GLOAD (pins issue site +
// forces register liveness) and s_waitcnt(memory) + sched_barrier(0) (pins
// all consumers below the wait). Validation: VGPR must be ~220+, no spill.

// Volatile asm load: pinned at issue site, register forced live.
#define GLOAD(dst, ptr)                                                      \
    asm volatile("global_load_dwordx4 %0, %1, off"                           \
                 : "=&v"(dst) : "v"(ptr))

// Drain our outstanding x loads. Loads were issued ~4 supersteps (~2000
// cyc) earlier -> the wait itself is free. sched_barrier(0) stops the
// machine scheduler from hoisting register-only consumers above it
// (rule #18: "memory" clobber alone does not order register ops).
#define XWAIT()                                                              \
    do {                                                                     \
        asm volatile("s_waitcnt vmcnt(0)" ::: "memory");                     \
        __builtin_amdgcn_sched_barrier(0);                                   \
    } while (0)

// Kernel 1: transpose-through-LDS [R15: 89 -> ~19us], f16 out [R16].
__global__ void __launch_bounds__(512)
feat_kernel(const int* __restrict__ atom_i,
            const int* __restrict__ atom_j,
            const float* __restrict__ dist,
            const float* __restrict__ emb,
            uint4* __restrict__ xpair8) {
    __shared__ float lf[512 * 31 + 30];   // slot(t,c) = t*31 + c
    const int b = blockIdx.x;
    const int t = threadIdx.x;

    {
        const int bt = b * T + t;
        const int ai = atom_i[bt];
        const int aj = atom_j[bt];
        const float dd = dist[bt];
        const float mi = (ai != 0) ? 1.0f : 0.0f;
        const float mj = (aj != 0) ? 1.0f : 0.0f;
        const float* ei = &emb[ai * NF];
        const float* ej = &emb[aj * NF];
        float* row = &lf[t * 31];
#pragma unroll
        for (int c = 0; c < NF; ++c) row[c] = mi * ei[c];
#pragma unroll
        for (int c = 0; c < NF; ++c) row[10 + c] = mj * ej[c];
#pragma unroll
        for (int c = 0; c < NF; ++c) {
            float ctr = (float)(c + 1) * 0.7f;
            float df = ctr - dd;
            row[20 + c] = mi * fexp(-df * df);
        }
    }
    __syncthreads();

    uint4* ob = xpair8 + (long)b * 1920;
    for (int o = t; o < 1920; o += 512) {
        unsigned p  = (unsigned)o / 384u;
        unsigned c4 = (unsigned)o - p * 384u;
        union { _Float16 h[8]; uint4 u; } pk;
#pragma unroll
        for (int kx = 0; kx < 8; ++kx) {
            unsigned s = 4u * c4 + (unsigned)(kx >> 1);
            unsigned e = (unsigned)(kx & 1);
            unsigned f = (2u * p + e) * 1536u + s;
            unsigned tt = f / 30u;            // compiler -> magic mul
            unsigned cc = f - tt * 30u;
            pk.h[kx] = (_Float16)lf[tt * 31u + cc];
        }
        ob[o] = pk.u;
    }
}

// One fused superstep: one GRU step for BOTH chains, interleaved per
// statement so each chain's latency (LDS return, fdot2 deps, trans chain)
// is filled by the other chain's independent issue. Both chains' 4x
// ds_read_b128 issue back-to-back (latencies overlap in one window); the
// ih dots (no h dependency) fill that window; hh dot loops carry A and B
// adjacently; trans ops strictly alternate A/B. R23 tree kept.
#define STEP2(PAR, XQA, XQB, IDX)                                            \
    {                                                                        \
        const uint4* hvA = (const uint4*)&hbufA[PAR][half * 32];             \
        const uint4* hvB = (const uint4*)&hbufB[PAR][half * 32];             \
        uint4 ta0 = hvA[0], ta1 = hvA[1], ta2 = hvA[2], ta3 = hvA[3];        \
        uint4 tb0 = hvB[0], tb1 = hvB[1], tb2 = hvB[2], tb3 = hvB[3];        \
        v2h xcA[5], xcB[5];                                                  \
        _Pragma("unroll")                                                    \
        for (int pp = 0; pp < 5; ++pp) {                                     \
            unsigned wa = ((const unsigned*)&XQA[pp])[IDX];                  \
            __builtin_memcpy(&xcA[pp], &wa, 4);                              \
            unsigned wb = ((const unsigned*)&XQB[pp])[IDX];                  \
            __builtin_memcpy(&xcB[pp], &wb, 4);                              \
        }                                                                    \
        float arA0 = brf, azA0 = bzf, aiA = bif, ahA0 = bhf;                 \
        float arB0 = brf, azB0 = bzf, aiB = bif, ahB0 = bhf;                 \
        _Pragma("unroll")                                                    \
        for (int d = 0; d < 5; ++d) {                                        \
            arA0 = fd(wir[d], xcA[d], arA0);                                 \
            arB0 = fd(wir[d], xcB[d], arB0);                                 \
            azA0 = fd(wiz[d], xcA[d], azA0);                                 \
            azB0 = fd(wiz[d], xcB[d], azB0);                                 \
            aiA  = fd(win[d], xcA[d], aiA);                                  \
            aiB  = fd(win[d], xcB[d], aiB);                                  \
        }                                                                    \
        v2h hjA[16], hjB[16];                                                \
        __builtin_memcpy(&hjA[0], &ta0, 16);                                 \
        __builtin_memcpy(&hjA[4], &ta1, 16);                                 \
        __builtin_memcpy(&hjA[8], &ta2, 16);                                 \
        __builtin_memcpy(&hjA[12], &ta3, 16);                                \
        __builtin_memcpy(&hjB[0], &tb0, 16);                                 \
        __builtin_memcpy(&hjB[4], &tb1, 16);                                 \
        __builtin_memcpy(&hjB[8], &tb2, 16);                                 \
        __builtin_memcpy(&hjB[12], &tb3, 16);                                \
        float arA1 = 0.0f, arA2 = 0.0f, arA3 = 0.0f;                         \
        float azA1 = 0.0f, azA2 = 0.0f, azA3 = 0.0f;                         \
        float ahA1 = 0.0f, ahA2 = 0.0f;                                      \
        float arB1 = 0.0f, arB2 = 0.0f, arB3 = 0.0f;                         \
        float azB1 = 0.0f, azB2 = 0.0f, azB3 = 0.0f;                         \
        float ahB1 = 0.0f, ahB2 = 0.0f;                                      \
        _Pragma("unroll")                                                    \
        for (int j = 0; j < 5; ++j) {                                        \
            arA1 = fd(whr[j], hjA[j], arA1);                                 \
            arB1 = fd(whr[j], hjB[j], arB1);                                 \
            azA1 = fd(whz[j], hjA[j], azA1);                                 \
            azB1 = fd(whz[j], hjB[j], azB1);                                 \
            ahA0 = fd(whn[j], hjA[j], ahA0);                                 \
            ahB0 = fd(whn[j], hjB[j], ahB0);                                 \
        }                                                                    \
        _Pragma("unroll")                                                    \
        for (int j = 5; j < 10; ++j) {                                       \
            arA2 = fd(whr[j], hjA[j], arA2);                                 \
            arB2 = fd(whr[j], hjB[j], arB2);                                 \
            azA2 = fd(whz[j], hjA[j], azA2);                                 \
            azB2 = fd(whz[j], hjB[j], azB2);                                 \
            ahA1 = fd(whn[j], hjA[j], ahA1);                                 \
            ahB1 = fd(whn[j], hjB[j], ahB1);                                 \
        }                                                                    \
        _Pragma("unroll")                                                    \
        for (int j = 10; j < 15; ++j) {                                      \
            arA3 = fd(whr[j], hjA[j], arA3);                                 \
            arB3 = fd(whr[j], hjB[j], arB3);                                 \
            azA3 = fd(whz[j], hjA[j], azA3);                                 \
            azB3 = fd(whz[j], hjB[j], azB3);                                 \
            ahA2 = fd(whn[j], hjA[j], ahA2);                                 \
            ahB2 = fd(whn[j], hjB[j], ahB2);                                 \
        }                                                                    \
        float arA = (arA0 + arA1) + (arA2 + arA3);                           \
        float arB = (arB0 + arB1) + (arB2 + arB3);                           \
        float azA = (azA0 + azA1) + (azA2 + azA3);                           \
        float azB = (azB0 + azB1) + (azB2 + azB3);                           \
        float ahA = (ahA0 + ahA1) + ahA2;                                    \
        float ahB = (ahB0 + ahB1) + ahB2;                                    \
        float erA = __builtin_amdgcn_exp2f(arA);                             \
        float erB = __builtin_amdgcn_exp2f(arB);                             \
        float ezA = __builtin_amdgcn_exp2f(azA);                             \
        float ezB = __builtin_amdgcn_exp2f(azB);                             \
        float rgA = frcp(1.0f + erA);                                        \
        float rgB = frcp(1.0f + erB);                                        \
        float zgA = frcp(1.0f + ezA);                                        \
        float zgB = frcp(1.0f + ezB);                                        \
        float ngA = 2.0f * frcp(1.0f +                                       \
                    __builtin_amdgcn_exp2f(aiA + rgA * ahA)) - 1.0f;         \
        float ngB = 2.0f * frcp(1.0f +                                       \
                    __builtin_amdgcn_exp2f(aiB + rgB * ahB)) - 1.0f;         \
        hA = ngA + zgA * (hA - ngA);                                         \
        hB = ngB + zgB * (hB - ngB);                                         \
        hbufA[(PAR) ^ 1][half * 32 + k] = (_Float16)hA;                      \
        hbufB[(PAR) ^ 1][half * 32 + k] = (_Float16)hB;                      \
        __builtin_amdgcn_fence(__ATOMIC_ACQ_REL, "wavefront");               \
    }

// Kernel 2: GRU recurrence — R26: 4 batches per wave as TWO independent
// interleaved chains (each chain = R18's lockstep 2-batch full-dot
// mapping), 512 single-wave blocks, deterministic volatile-asm x staging
// (counted-wait discipline: waits ~4 supersteps after their loads; never
// a demand wait). waves_per_eu(1,1): 1 resident wave -> VGPR cap 512;
// expected usage ~230.
__attribute__((amdgpu_waves_per_eu(1, 1)))
__global__ void __launch_bounds__(64)
gru_kernel(const _Float16* __restrict__ xpair,
           const float* __restrict__ W_ih,   // [90,10]
           const float* __restrict__ W_hh,   // [90,30]
           const float* __restrict__ b_ih,   // [90]
           const float* __restrict__ b_hh,   // [90]
           const float* __restrict__ W_out,  // [1,30]
           const float* __restrict__ b_out,  // [1]
           float* __restrict__ out) {
    __shared__ __align__(16) _Float16 hbufA[2][64];
    __shared__ __align__(16) _Float16 hbufB[2][64];
    const int lane = threadIdx.x;
    const int half = lane >> 5;
    const int k    = lane & 31;
    const bool active = (k < HID);
    const int kk = active ? k : (HID - 1);
    const int bA = blockIdx.x * 4 + half;      // chain A batches: 4B, 4B+1
    const int bB = bA + 2;                     // chain B batches: 4B+2, 4B+3

    const float SRZ = -LOG2E;          // sigmoid(x) = rcp(1+exp2(-L x))
    const float SN  = -2.0f * LOG2E;   // tanh(u) = 2 rcp(1+exp2(-2L u)) - 1

    // hh weights: 15 v2h (j-pairs) per gate, prescaled in f32 then RNE->f16.
    v2h whr[15], whz[15], whn[15];
    {
        const float2* Rr = (const float2*)&W_hh[(0 * HID + kk) * HID];
        const float2* Rz = (const float2*)&W_hh[(1 * HID + kk) * HID];
        const float2* Rn = (const float2*)&W_hh[(2 * HID + kk) * HID];
#pragma unroll
        for (int j = 0; j < 15; ++j) {
            float2 tr = Rr[j], tz = Rz[j], tn = Rn[j];
            whr[j] = (v2h){(_Float16)(tr.x * SRZ), (_Float16)(tr.y * SRZ)};
            whz[j] = (v2h){(_Float16)(tz.x * SRZ), (_Float16)(tz.y * SRZ)};
            whn[j] = (v2h){(_Float16)(tn.x * SN),  (_Float16)(tn.y * SN)};
        }
    }
    // ih weights: 5 v2h per gate (d-pairs match xpair layout).
    v2h wir[5], wiz[5], win[5];
    {
        const float2* Rr = (const float2*)&W_ih[(0 * HID + kk) * NF];
        const float2* Rz = (const float2*)&W_ih[(1 * HID + kk) * NF];
        const float2* Rn = (const float2*)&W_ih[(2 * HID + kk) * NF];
#pragma unroll
        for (int d = 0; d < 5; ++d) {
            float2 tr = Rr[d], tz = Rz[d], tn = Rn[d];
            wir[d] = (v2h){(_Float16)(tr.x * SRZ), (_Float16)(tr.y * SRZ)};
            wiz[d] = (v2h){(_Float16)(tz.x * SRZ), (_Float16)(tz.y * SRZ)};
            win[d] = (v2h){(_Float16)(tn.x * SN),  (_Float16)(tn.y * SN)};
        }
    }
    // Biases (prescaled, f32 — fdot2's accumulator seed). Chain-invariant.
    const float brf = SRZ * (b_ih[0 * HID + kk] + b_hh[0 * HID + kk]);
    const float bzf = SRZ * (b_ih[1 * HID + kk] + b_hh[1 * HID + kk]);
    const float bif = SN * b_ih[2 * HID + kk];  // n biases stay split:
    const float bhf = SN * b_hh[2 * HID + kk];  // n uses ai + rg*ah

    // Per-chain chunk streams: x[p][c] = uint4 = d-pair (2p,2p+1), steps
    // 4c..4c+3.
    const _Float16* xbA = xpair + (long)bA * FEAT_PER_B;
    const _Float16* xbB = xpair + (long)bB * FEAT_PER_B;
    const uint4* xaA[5];
    const uint4* xaB[5];
#pragma unroll
    for (int p = 0; p < 5; ++p) {
        xaA[p] = (const uint4*)(xbA + p * 3072);
        xaB[p] = (const uint4*)(xbB + p * 3072);
    }

    hbufA[0][lane] = (_Float16)0.0f;
    hbufA[1][lane] = (_Float16)0.0f;
    hbufB[0][lane] = (_Float16)0.0f;
    hbufB[1][lane] = (_Float16)0.0f;
    __builtin_amdgcn_fence(__ATOMIC_ACQ_REL, "wavefront");

    float hA = 0.0f, hB = 0.0f;
    uint4 xqA0[5], xqA1[5], xqB0[5], xqB1[5];
#pragma unroll
    for (int p = 0; p < 5; ++p) {
        GLOAD(xqA0[p], xaA[p]);
        GLOAD(xqB0[p], xaB[p]);
    }
    XWAIT();

    // 384 chunks of 4 supersteps. Steady state: issue the other buffer's 10
    // loads at a group top, run 4 supersteps (~2000 cyc) on the current
    // buffer, THEN wait — the wait is always ~4 supersteps after its loads.
    for (int c2 = 0; c2 < 384; c2 += 2) {
#pragma unroll
        for (int p = 0; p < 5; ++p) {
            GLOAD(xqA1[p], xaA[p] + c2 + 1);
            GLOAD(xqB1[p], xaB[p] + c2 + 1);
        }
        STEP2(0, xqA0, xqB0, 0);
        STEP2(1, xqA0, xqB0, 1);
        STEP2(0, xqA0, xqB0, 2);
        STEP2(1, xqA0, xqB0, 3);
        XWAIT();
        const int cn = (c2 + 2 < 384) ? (c2 + 2) : 383;
#pragma unroll
        for (int p = 0; p < 5; ++p) {
            GLOAD(xqA0[p], xaA[p] + cn);
            GLOAD(xqB0[p], xaB[p] + cn);
        }
        STEP2(0, xqA1, xqB1, 0);
        STEP2(1, xqA1, xqB1, 1);
        STEP2(0, xqA1, xqB1, 2);
        STEP2(1, xqA1, xqB1, 3);
        XWAIT();
    }

    // out[b] = relu(h . W_out + b_out), reduced within each 32-lane half,
    // once per chain.
    {
        float v = active ? hA * W_out[kk] : 0.0f;
#pragma unroll
        for (int off = 16; off; off >>= 1) v += __shfl_xor(v, off, 32);
        if (k == 0) {
            float o = v + b_out[0];
            out[bA] = o > 0.0f ? o : 0.0f;
        }
    }
    {
        float v = active ? hB * W_out[kk] : 0.0f;
#pragma unroll
        for (int off = 16; off; off >>= 1) v += __shfl_xor(v, off, 32);
        if (k == 0) {
            float o = v + b_out[0];
            out[bB] = o > 0.0f ? o : 0.0f;
        }
    }
}

extern "C" void kernel_launch(void* const* d_in, const int* in_sizes, int n_in,
                              void* d_out, int out_size, void* d_ws, size_t ws_size,
                              hipStream_t stream) {
    const int* atom_i   = (const int*)d_in[0];
    const int* atom_j   = (const int*)d_in[1];
    const float* dist   = (const float*)d_in[2];
    const float* emb    = (const float*)d_in[3];
    const float* W_ih   = (const float*)d_in[4];
    const float* W_hh   = (const float*)d_in[5];
    const float* b_ih   = (const float*)d_in[6];
    const float* b_hh   = (const float*)d_in[7];
    const float* W_out  = (const float*)d_in[8];
    const float* b_out  = (const float*)d_in[9];
    float* out = (float*)d_out;
    _Float16* xpair = (_Float16*)d_ws;   // 62,914,560 B

    feat_kernel<<<BATCH, 512, 0, stream>>>(atom_i, atom_j, dist, emb,
                                           (uint4*)xpair);
    gru_kernel<<<BATCH / 4, 64, 0, stream>>>(xpair, W_ih, W_hh, b_ih, b_hh,
                                             W_out, b_out, out);
}